// Round 3
// baseline (650.386 us; speedup 1.0000x reference)
//
#include <hip/hip_runtime.h>

#define B_SZ 2
#define T_SZ 4096
#define H_N  8

typedef unsigned short u16;
typedef __attribute__((ext_vector_type(8))) short short8;
typedef __attribute__((ext_vector_type(4))) float f32x4;
typedef __attribute__((ext_vector_type(4))) unsigned short u16x4;

__device__ __forceinline__ u16 f2bf(float f) {
    unsigned int u;
    __builtin_memcpy(&u, &f, 4);
    u = (u + 0x7fffu + ((u >> 16) & 1u)) >> 16;
    return (u16)u;
}
__device__ __forceinline__ f32x4 mfma16(short8 a, short8 b, f32x4 c) {
    return __builtin_amdgcn_mfma_f32_16x16x32_bf16(a, b, c, 0, 0, 0);
}

// ---------- f32 -> bf16 elementwise, 4 elems/thread ----------
__global__ void k_cvt(const float* __restrict__ src, u16* __restrict__ dst) {
    int i = (blockIdx.x * 256 + threadIdx.x) * 4;
    float4 v = *(const float4*)(src + i);
    u16x4 o = { f2bf(v.x), f2bf(v.y), f2bf(v.z), f2bf(v.w) };
    *(u16x4*)(dst + i) = o;
}

// ---------- f32 [K][N] -> bf16 [N][K] (convert + transpose) ----------
__global__ void k_cvt_t(const float* __restrict__ src, u16* __restrict__ dst, int K, int N) {
    int idx = blockIdx.x * 256 + threadIdx.x;
    int k = idx / N, n = idx - k * N;
    dst[(size_t)n * K + k] = f2bf(src[idx]);
}

// ---------- GEMM: C[M,N] = A[M,512] x Bt[N,512]^T (+ optional f32 bias[N]) ----------
// block = 256 (4 waves); tile 64(M) x 64(N); wave w owns n-cols w*16..w*16+15.
// OutT = u16 (bf16 store) for intermediates, float for the final output (harness
// d_out is f32 because the reference returns float32).
template <typename OutT>
__global__ __launch_bounds__(256) void k_gemm(const u16* __restrict__ A, const u16* __restrict__ Bt,
                                              const float* __restrict__ bias, OutT* __restrict__ C,
                                              int M, int N) {
    const int K = 512;
    int m0 = blockIdx.x * 64;
    int tid = threadIdx.x;
    int wave = tid >> 6, lane = tid & 63, l16 = lane & 15, quad = lane >> 4;
    int ncol = blockIdx.y * 64 + wave * 16 + l16;

    f32x4 acc[4];
#pragma unroll
    for (int i = 0; i < 4; ++i) acc[i] = (f32x4){0.f, 0.f, 0.f, 0.f};

    const u16* bp = Bt + (size_t)ncol * K + quad * 8;            // B[n=l16][k=quad*8+j]
    const u16* ap = A + (size_t)(m0 + l16) * K + quad * 8;       // A[m=l16][k=quad*8+j]

    for (int k0 = 0; k0 < K; k0 += 32) {
        short8 bfr = *(const short8*)(bp + k0);
#pragma unroll
        for (int i = 0; i < 4; ++i) {
            short8 afr = *(const short8*)(ap + (size_t)(i * 16) * K + k0);
            acc[i] = mfma16(afr, bfr, acc[i]);
        }
    }

    float bb = bias ? bias[ncol] : 0.f;
#pragma unroll
    for (int i = 0; i < 4; ++i)
#pragma unroll
        for (int r = 0; r < 4; ++r) {
            int row = m0 + i * 16 + quad * 4 + r;                // C/D: row=quad*4+reg, col=l16
            float val = acc[i][r] + bb;
            if constexpr (__is_same(OutT, float)) {
                C[(size_t)row * N + ncol] = val;
            } else {
                C[(size_t)row * N + ncol] = f2bf(val);
            }
        }
}

// ---------- flash attention ----------
// grid (T/64, H, B); block 256 = 4 waves; wave owns 16 q rows. Key tiles of 32.
// qk layout: [B*T, 1024] (q cols 0..511, k cols 512..1023), per-head slice h*64.
// v layout:  [B*T, 512]. Output o: [B*T, 512] bf16.
__global__ __launch_bounds__(256) void k_flash(const u16* __restrict__ qk, const u16* __restrict__ v,
                                               u16* __restrict__ o) {
    const float SCALE = 0.35355339059327373f; // (DH//H)^-0.5 = 8^-0.5, faithful to reference
    int qt = blockIdx.x, h = blockIdx.y, b = blockIdx.z;
    int tid = threadIdx.x;
    int wave = tid >> 6, lane = tid & 63, l16 = lane & 15, quad = lane >> 4;

    __shared__ u16 Vt[64][40];      // V^T tile: [d][key], rows padded to 80B (16B-aligned, 2-way banks)
    __shared__ u16 P[4][16][40];    // per-wave P tile: [qrow][key]

    // Q fragments (A-layout): m=l16 -> q row = wave*16+l16; k = quad*8+j over d
    const u16* qrow = qk + (size_t)(b * T_SZ + qt * 64 + wave * 16 + l16) * 1024 + h * 64 + quad * 8;
    short8 qf0 = *(const short8*)(qrow);
    short8 qf1 = *(const short8*)(qrow + 32);

    const u16* kbase = qk + (size_t)b * T_SZ * 1024 + 512 + h * 64;
    const u16* vbase = v + (size_t)b * T_SZ * 512 + h * 64;

    f32x4 oacc[4];
#pragma unroll
    for (int c = 0; c < 4; ++c) oacc[c] = (f32x4){0.f, 0.f, 0.f, 0.f};
    float m_i[4], l_i[4];
#pragma unroll
    for (int r = 0; r < 4; ++r) { m_i[r] = -3.0e38f; l_i[r] = 0.f; }

    int vr = tid >> 3;          // 0..31 : key row within tile
    int vc = (tid & 7) * 8;     // 0..56 : d offset

    for (int kt = 0; kt < T_SZ / 32; ++kt) {
        __syncthreads();  // prev iter's Vt/P reads complete
        // stage V^T cooperatively: 256 threads x 16B
        short8 vv = *(const short8*)(vbase + (size_t)(kt * 32 + vr) * 512 + vc);
#pragma unroll
        for (int j = 0; j < 8; ++j) Vt[vc + j][vr] = (u16)vv[j];

        // S = Q K^T : K B-frags (n=l16 -> key, k=quad*8+j -> d) straight from global
        const u16* kp = kbase + (size_t)(kt * 32) * 1024 + quad * 8;
        short8 k00 = *(const short8*)(kp + (size_t)l16 * 1024);
        short8 k01 = *(const short8*)(kp + (size_t)l16 * 1024 + 32);
        short8 k10 = *(const short8*)(kp + (size_t)(l16 + 16) * 1024);
        short8 k11 = *(const short8*)(kp + (size_t)(l16 + 16) * 1024 + 32);
        f32x4 s0 = (f32x4){0.f, 0.f, 0.f, 0.f};
        f32x4 s1 = (f32x4){0.f, 0.f, 0.f, 0.f};
        s0 = mfma16(qf0, k00, s0); s0 = mfma16(qf1, k01, s0);   // keys 0..15
        s1 = mfma16(qf0, k10, s1); s1 = mfma16(qf1, k11, s1);   // keys 16..31

        // online softmax; C-layout row = quad*4+r, col = l16 (key)
#pragma unroll
        for (int r = 0; r < 4; ++r) {
            float a0 = s0[r] * SCALE, a1 = s1[r] * SCALE;
            float mx = fmaxf(a0, a1);
            mx = fmaxf(mx, __shfl_xor(mx, 1));
            mx = fmaxf(mx, __shfl_xor(mx, 2));
            mx = fmaxf(mx, __shfl_xor(mx, 4));
            mx = fmaxf(mx, __shfl_xor(mx, 8));
            float mnew = fmaxf(m_i[r], mx);
            float p0 = __expf(a0 - mnew), p1 = __expf(a1 - mnew);
            float alpha = __expf(m_i[r] - mnew);   // first iter: exp(very negative) = 0
            float ls = p0 + p1;
            ls += __shfl_xor(ls, 1);
            ls += __shfl_xor(ls, 2);
            ls += __shfl_xor(ls, 4);
            ls += __shfl_xor(ls, 8);
            l_i[r] = l_i[r] * alpha + ls;
            m_i[r] = mnew;
#pragma unroll
            for (int c = 0; c < 4; ++c) oacc[c][r] *= alpha;
            P[wave][quad * 4 + r][l16] = f2bf(p0);
            P[wave][quad * 4 + r][16 + l16] = f2bf(p1);
        }
        __syncthreads();  // Vt staged + P visible

        // PV: A = P (m=l16 q row, k=quad*8+j key), B = V (k=key, n=l16 d within chunk c)
        short8 pf = *(const short8*)(&P[wave][l16][quad * 8]);
#pragma unroll
        for (int c = 0; c < 4; ++c) {
            short8 vf = *(const short8*)(&Vt[c * 16 + l16][quad * 8]);
            oacc[c] = mfma16(pf, vf, oacc[c]);
        }
    }

    u16* ob = o + (size_t)(b * T_SZ + qt * 64 + wave * 16) * 512 + h * 64;
#pragma unroll
    for (int r = 0; r < 4; ++r) {
        float inv = 1.f / l_i[r];
#pragma unroll
        for (int c = 0; c < 4; ++c)
            ob[(size_t)(quad * 4 + r) * 512 + c * 16 + l16] = f2bf(oacc[c][r] * inv);
    }
}

extern "C" void kernel_launch(void* const* d_in, const int* in_sizes, int n_in,
                              void* d_out, int out_size, void* d_ws, size_t ws_size,
                              hipStream_t stream) {
    const float* x    = (const float*)d_in[0];   // [2,4096,512] f32
    const float* cond = (const float*)d_in[1];   // [2,4096,512] f32
    const float* Wqk  = (const float*)d_in[2];   // [512,1024]   f32
    const float* Wv   = (const float*)d_in[3];   // [512,512]    f32
    const float* Wu   = (const float*)d_in[4];   // [512,512]    f32
    const float* bu   = (const float*)d_in[5];   // [512]        f32
    float* out = (float*)d_out;                  // [2,4096,512] f32 (reference output dtype)

    const size_t MT = (size_t)B_SZ * T_SZ;       // 8192
    u16* xb    = (u16*)d_ws;                     // [8192,512]   8 MB
    u16* cb    = xb + MT * 512;                  // [8192,512]   8 MB
    u16* qk_ws = cb + MT * 512;                  // [8192,1024] 16 MB
    u16* v_ws  = qk_ws + MT * 1024;              // [8192,512]   8 MB
    u16* at_ws = v_ws + MT * 512;                // [8192,512]   8 MB
    u16* Wqk_t = at_ws + MT * 512;               // [1024,512]   1 MB
    u16* Wv_t  = Wqk_t + (size_t)1024 * 512;     // [512,512]  0.5 MB
    u16* Wu_t  = Wv_t + (size_t)512 * 512;       // [512,512]  0.5 MB

    k_cvt<<<(int)(MT * 512 / 1024), 256, 0, stream>>>(x, xb);
    k_cvt<<<(int)(MT * 512 / 1024), 256, 0, stream>>>(cond, cb);
    k_cvt_t<<<(512 * 1024) / 256, 256, 0, stream>>>(Wqk, Wqk_t, 512, 1024);
    k_cvt_t<<<(512 * 512) / 256, 256, 0, stream>>>(Wv, Wv_t, 512, 512);
    k_cvt_t<<<(512 * 512) / 256, 256, 0, stream>>>(Wu, Wu_t, 512, 512);

    k_gemm<u16><<<dim3(128, 16), 256, 0, stream>>>(cb, Wqk_t, nullptr, qk_ws, 8192, 1024);
    k_gemm<u16><<<dim3(128, 8), 256, 0, stream>>>(xb, Wv_t, nullptr, v_ws, 8192, 512);
    k_flash<<<dim3(64, 8, 2), 256, 0, stream>>>(qk_ws, v_ws, at_ws);
    k_gemm<float><<<dim3(128, 8), 256, 0, stream>>>(at_ws, Wu_t, bu, out, 8192, 512);
}